// Round 1
// baseline (760.574 us; speedup 1.0000x reference)
//
#include <hip/hip_runtime.h>
#include <cstdint>
#include <cstddef>

// ---------------------------------------------------------------------------
// GCN forward: logit = adj @ (relu(adj @ (x@W1) + b1) @ W2) + b2
// N=8192, F_IN=512, N_CLASSES=345 (padded to 384 internally).
// Strategy: bf16 MFMA (16x16x32) GEMM chain; adj converted to bf16 once in ws
// when ws_size permits, else converted during LDS staging.
// ---------------------------------------------------------------------------

#define NN 8192
#define FIN 512
#define NCLS 345
#define NCLS_PAD 384

typedef __attribute__((ext_vector_type(8))) short bf16x8;
typedef __attribute__((ext_vector_type(4))) float f32x4;

__device__ __forceinline__ unsigned short f2bf(float f) {
  unsigned u = __float_as_uint(f);
  u += 0x7fffu + ((u >> 16) & 1u);   // RTNE
  return (unsigned short)(u >> 16);
}

// ---- transpose+convert small weight matrices: out[n][k] = bf16(in[k][n]) ----
// out is [Npad][K]; rows n in [Nin, Npad) are zero-filled.
__global__ void tconv_kernel(const float* __restrict__ in, unsigned short* __restrict__ out,
                             int K, int Nin, int Npad) {
  __shared__ float t[32][33];
  int kb = blockIdx.x * 32, nb = blockIdx.y * 32;
  int x = threadIdx.x, y = threadIdx.y;
#pragma unroll
  for (int i = 0; i < 32; i += 8) {
    int k = kb + y + i, n = nb + x;
    t[y + i][x] = (n < Nin) ? in[(size_t)k * Nin + n] : 0.0f;
  }
  __syncthreads();
#pragma unroll
  for (int i = 0; i < 32; i += 8) {
    int n = nb + y + i, k = kb + x;
    out[(size_t)n * K + k] = f2bf(t[x][y + i]);
  }
}

// ---- bulk fp32 -> bf16 convert (adj) ----
__global__ void conv_adj_kernel(const float* __restrict__ in, unsigned short* __restrict__ out) {
  size_t i = ((size_t)blockIdx.x * 256 + threadIdx.x) * 4;
  float4 v = *(const float4*)(in + i);
  ushort4 w;
  w.x = f2bf(v.x); w.y = f2bf(v.y); w.z = f2bf(v.z); w.w = f2bf(v.w);
  *(ushort4*)(out + i) = w;
}

// ---------------------------------------------------------------------------
// GEMM: C[M][N] = A[M][K] * B[K][N] (+bias, relu), B given TRANSPOSED as
// Bt[N][K] bf16. A either fp32 (converted in staging) or bf16.
// Tile 128x128, BK=64, 256 threads (4 waves, 2x2 of 64x64 each).
// OMODE: 0 = fp32 natural, n < nbound, row stride ldc
//        1 = bf16 natural [M][ldc]
//        2 = bf16 transposed: out[n][m], row stride ldc (=M)
// ---------------------------------------------------------------------------
template <bool ABF, int OMODE, bool BIAS, bool RELU>
__global__ __launch_bounds__(256, 1) void gemm_kernel(
    const void* __restrict__ Ap, const unsigned short* __restrict__ Bt,
    const float* __restrict__ bias, void* __restrict__ Cp,
    const int M, const int N, const int K, const int ldc, const int nbound) {
  __shared__ __align__(16) char smem[32768];  // [0,16K): A tile, [16K,32K): B tile

  const int tid = threadIdx.x;
  const int lane = tid & 63, wave = tid >> 6;
  const int wr = wave >> 1, wc = wave & 1;
  const int ln15 = lane & 15, lhi = lane >> 4;

  const int gn = N >> 7;
  int bid = blockIdx.x;
  { // XCD-bijective swizzle (grid sizes here are multiples of 8)
    const int q = (int)gridDim.x >> 3;
    bid = (bid & 7) * q + (bid >> 3);
  }
  const int bm = (bid / gn) << 7;
  const int bn = (bid % gn) << 7;

  // staging mapping: thread -> (row sm of tile, k-half sk)
  const int sm = tid >> 1;
  const int sk = (tid & 1) << 5;
  const int wxor = (sm & 7) << 4;
  const int wbaseA = sm * 128;
  const int wbaseB = 16384 + sm * 128;

  const float* Af = (const float*)Ap;
  const unsigned short* Ab = (const unsigned short*)Ap;
  const size_t arow = (size_t)(bm + sm) * K + sk;
  const unsigned short* Bsrc = Bt + (size_t)(bn + sm) * K + sk;

  // fragment read base addresses (K-step invariant; mi/ni via +2048*idx imm)
  int a_base[2], b_base[2];
#pragma unroll
  for (int kh = 0; kh < 2; kh++) {
    int kb = ((kh << 5) + (lhi << 3)) << 1;        // k byte offset in row
    int kx = kb ^ ((ln15 & 7) << 4);
    a_base[kh] = (wr * 64 + ln15) * 128 + kx;
    b_base[kh] = 16384 + (wc * 64 + ln15) * 128 + kx;
  }

  f32x4 acc[4][4];
#pragma unroll
  for (int i = 0; i < 4; i++)
#pragma unroll
    for (int j = 0; j < 4; j++) acc[i][j] = (f32x4)(0.0f);

  // prefetch registers
  float4 pf[8];
  bf16x8 pa[4];
  bf16x8 pb[4];

  auto load_A = [&](int k0) {
    if constexpr (ABF) {
      const unsigned short* s = Ab + arow + k0;
#pragma unroll
      for (int j = 0; j < 4; j++) pa[j] = *(const bf16x8*)(s + 8 * j);
    } else {
      const float* s = Af + arow + k0;
#pragma unroll
      for (int j = 0; j < 8; j++) pf[j] = *(const float4*)(s + 4 * j);
    }
  };
  auto load_B = [&](int k0) {
    const unsigned short* s = Bsrc + k0;
#pragma unroll
    for (int j = 0; j < 4; j++) pb[j] = *(const bf16x8*)(s + 8 * j);
  };

  load_A(0);
  load_B(0);

  for (int k0 = 0; k0 < K; k0 += 64) {
    __syncthreads();  // previous compute done reading LDS
    // ---- store prefetched tile to LDS (swizzled) ----
    if constexpr (ABF) {
#pragma unroll
      for (int j = 0; j < 4; j++) {
        int off = wbaseA + ((sk * 2 + 16 * j) ^ wxor);
        *(bf16x8*)(smem + off) = pa[j];
      }
    } else {
#pragma unroll
      for (int j = 0; j < 8; j++) {
        ushort4 v;
        v.x = f2bf(pf[j].x); v.y = f2bf(pf[j].y);
        v.z = f2bf(pf[j].z); v.w = f2bf(pf[j].w);
        int off = wbaseA + (((sk + 4 * j) * 2) ^ wxor);
        *(ushort4*)(smem + off) = v;
      }
    }
#pragma unroll
    for (int j = 0; j < 4; j++) {
      int off = wbaseB + ((sk * 2 + 16 * j) ^ wxor);
      *(bf16x8*)(smem + off) = pb[j];
    }
    __syncthreads();

    // ---- issue next tile's global loads (latency hidden under MFMA) ----
    int kn = k0 + 64;
    if (kn >= K) kn = 0;  // dummy re-load on last iter (discarded)
    load_A(kn);
    load_B(kn);

    // ---- compute: 2 k-halves x 16 MFMA ----
#pragma unroll
    for (int kh = 0; kh < 2; kh++) {
      bf16x8 afr[4], bfr[4];
#pragma unroll
      for (int mi = 0; mi < 4; mi++)
        afr[mi] = *(const bf16x8*)(smem + a_base[kh] + mi * 2048);
#pragma unroll
      for (int ni = 0; ni < 4; ni++)
        bfr[ni] = *(const bf16x8*)(smem + b_base[kh] + ni * 2048);
#pragma unroll
      for (int mi = 0; mi < 4; mi++)
#pragma unroll
        for (int ni = 0; ni < 4; ni++)
          acc[mi][ni] = __builtin_amdgcn_mfma_f32_16x16x32_bf16(
              afr[mi], bfr[ni], acc[mi][ni], 0, 0, 0);
    }
  }

  // ---- epilogue ----
  // C/D layout (16x16x32): col = lane&15, row = (lane>>4)*4 + reg  [m89]
  if constexpr (OMODE == 2) {
    unsigned short* Ct = (unsigned short*)Cp;
#pragma unroll
    for (int ni = 0; ni < 4; ni++) {
      int n = bn + wc * 64 + ni * 16 + ln15;
#pragma unroll
      for (int mi = 0; mi < 4; mi++) {
        int m0 = bm + wr * 64 + mi * 16 + (lhi << 2);
        ushort4 v;
        v.x = f2bf(acc[mi][ni][0]); v.y = f2bf(acc[mi][ni][1]);
        v.z = f2bf(acc[mi][ni][2]); v.w = f2bf(acc[mi][ni][3]);
        *(ushort4*)(Ct + (size_t)n * ldc + m0) = v;
      }
    }
  } else if constexpr (OMODE == 1) {
    unsigned short* Ch = (unsigned short*)Cp;
#pragma unroll
    for (int ni = 0; ni < 4; ni++) {
      int n = bn + wc * 64 + ni * 16 + ln15;
      float bv = BIAS ? bias[n] : 0.0f;
#pragma unroll
      for (int mi = 0; mi < 4; mi++) {
        int m0 = bm + wr * 64 + mi * 16 + (lhi << 2);
#pragma unroll
        for (int r = 0; r < 4; r++) {
          float v = acc[mi][ni][r] + bv;
          if (RELU) v = fmaxf(v, 0.0f);
          Ch[(size_t)(m0 + r) * ldc + n] = f2bf(v);
        }
      }
    }
  } else {
    float* Cf = (float*)Cp;
#pragma unroll
    for (int ni = 0; ni < 4; ni++) {
      int n = bn + wc * 64 + ni * 16 + ln15;
      if (n < nbound) {
        float bv = BIAS ? bias[n] : 0.0f;
#pragma unroll
        for (int mi = 0; mi < 4; mi++) {
          int m0 = bm + wr * 64 + mi * 16 + (lhi << 2);
#pragma unroll
          for (int r = 0; r < 4; r++) {
            float v = acc[mi][ni][r] + bv;
            if (RELU) v = fmaxf(v, 0.0f);
            Cf[(size_t)(m0 + r) * ldc + n] = v;
          }
        }
      }
    }
  }
}

// ---------------------------------------------------------------------------
extern "C" void kernel_launch(void* const* d_in, const int* in_sizes, int n_in,
                              void* d_out, int out_size, void* d_ws, size_t ws_size,
                              hipStream_t stream) {
  (void)in_sizes; (void)n_in; (void)out_size;
  const float* x   = (const float*)d_in[0];
  const float* adj = (const float*)d_in[1];
  const float* W1  = (const float*)d_in[2];
  const float* b1  = (const float*)d_in[3];
  const float* W2  = (const float*)d_in[4];
  const float* b2  = (const float*)d_in[5];

  char* w = (char*)d_ws;
  size_t off = 0;
  auto alloc = [&](size_t bytes) -> char* {
    char* p = w + off;
    off += (bytes + 255) & ~(size_t)255;
    return p;
  };
  unsigned short* W1T   = (unsigned short*)alloc((size_t)FIN * FIN * 2);
  unsigned short* W2T   = (unsigned short*)alloc((size_t)NCLS_PAD * FIN * 2);
  unsigned short* tmp1T = (unsigned short*)alloc((size_t)FIN * NN * 2);
  unsigned short* hbuf  = (unsigned short*)alloc((size_t)NN * FIN * 2);
  unsigned short* tmp2T = (unsigned short*)alloc((size_t)NCLS_PAD * NN * 2);
  const size_t adj_bytes = (size_t)NN * NN * 2;
  const bool big = (off + adj_bytes) <= ws_size;  // constant across calls
  unsigned short* adjb = big ? (unsigned short*)alloc(adj_bytes) : nullptr;

  dim3 blk(256);

  // weight transposes (tiny)
  tconv_kernel<<<dim3(FIN / 32, FIN / 32), dim3(32, 8), 0, stream>>>(W1, W1T, FIN, FIN, FIN);
  tconv_kernel<<<dim3(FIN / 32, NCLS_PAD / 32), dim3(32, 8), 0, stream>>>(W2, W2T, FIN, NCLS, NCLS_PAD);
  if (big)
    conv_adj_kernel<<<dim3((NN * (size_t)NN) / (256 * 4)), blk, 0, stream>>>(adj, adjb);

  // A: tmp1T = (x @ W1)^T        M=8192 N=512 K=512
  gemm_kernel<false, 2, false, false><<<dim3(64 * 4), blk, 0, stream>>>(
      x, W1T, nullptr, tmp1T, NN, FIN, FIN, NN, FIN);
  // B: h = relu(adj @ tmp1 + b1) M=8192 N=512 K=8192
  if (big)
    gemm_kernel<true, 1, true, true><<<dim3(64 * 4), blk, 0, stream>>>(
        adjb, tmp1T, b1, hbuf, NN, FIN, NN, FIN, FIN);
  else
    gemm_kernel<false, 1, true, true><<<dim3(64 * 4), blk, 0, stream>>>(
        adj, tmp1T, b1, hbuf, NN, FIN, NN, FIN, FIN);
  // C: tmp2T = (h @ W2)^T        M=8192 N=384 K=512
  gemm_kernel<true, 2, false, false><<<dim3(64 * 3), blk, 0, stream>>>(
      hbuf, W2T, nullptr, tmp2T, NN, NCLS_PAD, FIN, NN, NCLS_PAD);
  // D: out = adj @ tmp2 + b2     M=8192 N=384 K=8192, store n<345
  if (big)
    gemm_kernel<true, 0, true, false><<<dim3(64 * 3), blk, 0, stream>>>(
        adjb, tmp2T, b2, d_out, NN, NCLS_PAD, NN, NCLS, NCLS);
  else
    gemm_kernel<false, 0, true, false><<<dim3(64 * 3), blk, 0, stream>>>(
        adj, tmp2T, b2, d_out, NN, NCLS_PAD, NN, NCLS, NCLS);
}

// Round 4
// 650.562 us; speedup vs baseline: 1.1691x; 1.1691x over previous
//
#include <hip/hip_runtime.h>
#include <cstdint>
#include <cstddef>

// ---------------------------------------------------------------------------
// GCN forward: logit = adj @ (relu(adj @ (x@W1) + b1) @ W2) + b2
// N=8192, F_IN=512, N_CLASSES=345 (padded to 384 internally).
// bf16 MFMA GEMM chain + split-K (latency fix for 1-block/CU grids):
//   A: tmp1T = (x@W1)^T          KS=2, partials fp32 [512][8192] x2
//   B: h = relu(adj@tmp1 + b1)   KS=4, partials fp32 [512][8192] x4 -> hbuf
//   C: tmp2T = (h@W2)^T          KS=2
//   D: out = adj@tmp2 + b2       KS=4 -> fp32 out
// ---------------------------------------------------------------------------

#define NN 8192
#define FIN 512
#define NCLS 345
#define NCLS_PAD 384

typedef __attribute__((ext_vector_type(8))) short bf16x8;
typedef __attribute__((ext_vector_type(4))) float f32x4;

__device__ __forceinline__ unsigned short f2bf(float f) {
  unsigned u = __float_as_uint(f);
  u += 0x7fffu + ((u >> 16) & 1u);   // RTNE
  return (unsigned short)(u >> 16);
}

// ---- transpose+convert small weight matrices: out[n][k] = bf16(in[k][n]) ----
__global__ void tconv_kernel(const float* __restrict__ in, unsigned short* __restrict__ out,
                             int K, int Nin, int Npad) {
  __shared__ float t[32][33];
  int kb = blockIdx.x * 32, nb = blockIdx.y * 32;
  int x = threadIdx.x, y = threadIdx.y;
#pragma unroll
  for (int i = 0; i < 32; i += 8) {
    int k = kb + y + i, n = nb + x;
    t[y + i][x] = (n < Nin) ? in[(size_t)k * Nin + n] : 0.0f;
  }
  __syncthreads();
#pragma unroll
  for (int i = 0; i < 32; i += 8) {
    int n = nb + y + i, k = kb + x;
    out[(size_t)n * K + k] = f2bf(t[x][y + i]);
  }
}

// ---- bulk fp32 -> bf16 convert (adj) ----
__global__ void conv_adj_kernel(const float* __restrict__ in, unsigned short* __restrict__ out) {
  size_t i = ((size_t)blockIdx.x * 256 + threadIdx.x) * 4;
  float4 v = *(const float4*)(in + i);
  ushort4 w;
  w.x = f2bf(v.x); w.y = f2bf(v.y); w.z = f2bf(v.z); w.w = f2bf(v.w);
  *(ushort4*)(out + i) = w;
}

// ---- split-K reduce, elementwise (KS=2): out[n][m] bf16 = sum(P[s][n][m]) ----
__global__ void reduce_elem2(const float* __restrict__ P, unsigned short* __restrict__ out,
                             size_t total) {
  size_t i = ((size_t)blockIdx.x * 256 + threadIdx.x) * 4;
  float4 a = *(const float4*)(P + i);
  float4 b = *(const float4*)(P + total + i);
  ushort4 o;
  o.x = f2bf(a.x + b.x); o.y = f2bf(a.y + b.y);
  o.z = f2bf(a.z + b.z); o.w = f2bf(a.w + b.w);
  *(ushort4*)(out + i) = o;
}

// ---- split-K reduce + transpose: P is KS x [NW][M] fp32; out is [M][ldo] ----
// OUTF32=false: bf16 out (+bias +relu)   OUTF32=true: fp32 out (+bias), n<nbound
template <int KS, bool RELU, bool OUTF32>
__global__ void reduce_trans(const float* __restrict__ P, const float* __restrict__ bias,
                             void* __restrict__ out, const int M, const int NW,
                             const int nbound, const int ldo) {
  __shared__ float t[64][65];
  const int tm = blockIdx.x, tn = blockIdx.y;
  const int tid = threadIdx.x;
  const int nl = tid >> 4, m4 = (tid & 15) << 2;
  const size_t SS = (size_t)NW * M;
#pragma unroll
  for (int p = 0; p < 4; p++) {
    int nr = p * 16 + nl;
    const float* src = P + (size_t)(tn * 64 + nr) * M + tm * 64 + m4;
    float4 s = *(const float4*)src;
#pragma unroll
    for (int ksl = 1; ksl < KS; ksl++) {
      float4 v = *(const float4*)(src + (size_t)ksl * SS);
      s.x += v.x; s.y += v.y; s.z += v.z; s.w += v.w;
    }
    t[nr][m4 + 0] = s.x; t[nr][m4 + 1] = s.y;
    t[nr][m4 + 2] = s.z; t[nr][m4 + 3] = s.w;
  }
  __syncthreads();
#pragma unroll
  for (int p = 0; p < 4; p++) {
    int ml = p * 16 + (tid >> 4);
    int n0 = (tid & 15) << 2;
    int m = tm * 64 + ml;
    int ng = tn * 64 + n0;
    float v[4];
#pragma unroll
    for (int j = 0; j < 4; j++) {
      float bv = (ng + j < nbound) ? bias[ng + j] : 0.0f;
      v[j] = t[n0 + j][ml] + bv;
      if (RELU) v[j] = fmaxf(v[j], 0.0f);
    }
    if (OUTF32) {
      float* of = (float*)out;
#pragma unroll
      for (int j = 0; j < 4; j++)
        if (ng + j < nbound) of[(size_t)m * ldo + ng + j] = v[j];
    } else {
      ushort4 o;
      o.x = f2bf(v[0]); o.y = f2bf(v[1]); o.z = f2bf(v[2]); o.w = f2bf(v[3]);
      *(ushort4*)((unsigned short*)out + (size_t)m * ldo + ng) = o;
    }
  }
}

// ---------------------------------------------------------------------------
// GEMM: C[M][N] = A[M][K] * B[K][N], B given transposed as Bt[N][K] bf16.
// Tile 128x128, BK=64, 256 threads (4 waves, 2x2 of 64x64 each).
// OMODE: 0 fp32 natural (+bias,+relu opts, n<nbound) | 1 bf16 natural |
//        2 bf16 transposed [N][M] | 4 fp32 partial transposed [N][M] slice ks
// KS: split-K factor (grid = tiles*KS). KS>1 requires OMODE==4.
// ---------------------------------------------------------------------------
template <bool ABF, int OMODE, bool BIAS, bool RELU, int KS>
__global__ __launch_bounds__(256, 4) void gemm_kernel(
    const void* __restrict__ Ap, const unsigned short* __restrict__ Bt,
    const float* __restrict__ bias, void* __restrict__ Cp,
    const int M, const int N, const int K, const int ldc, const int nbound) {
  __shared__ __align__(16) char smem[32768];  // [0,16K): A tile, [16K,32K): B tile

  const int tid = threadIdx.x;
  const int lane = tid & 63, wave = tid >> 6;
  const int wr = wave >> 1, wc = wave & 1;
  const int ln15 = lane & 15, lhi = lane >> 4;

  int bid = blockIdx.x;
  { // XCD-bijective swizzle (all grids here are multiples of 8)
    const int q = (int)gridDim.x >> 3;
    bid = (bid & 7) * q + (bid >> 3);
  }
  const int gn = N >> 7;
  int bmi, bnid, ks;
  if constexpr (KS == 1) {
    bmi = bid / gn; bnid = bid % gn; ks = 0;
  } else {
    bnid = bid % gn;
    int t = bid / gn;
    ks = t % KS; bmi = t / KS;
  }
  const int bm = bmi << 7;
  const int bn = bnid << 7;
  const int Kc = K / KS;
  const int kbeg = ks * Kc;
  const int kend = kbeg + Kc;

  // staging mapping: thread -> (row sm of tile, k-half sk)
  const int sm = tid >> 1;
  const int sk = (tid & 1) << 5;
  const int wxor = (sm & 7) << 4;
  const int wbaseA = sm * 128;
  const int wbaseB = 16384 + sm * 128;

  const float* Af = (const float*)Ap;
  const unsigned short* Ab = (const unsigned short*)Ap;
  const size_t arow = (size_t)(bm + sm) * K + sk;
  const unsigned short* Bsrc = Bt + (size_t)(bn + sm) * K + sk;

  // fragment read base addresses
  int a_base[2], b_base[2];
#pragma unroll
  for (int kh = 0; kh < 2; kh++) {
    int kb = ((kh << 5) + (lhi << 3)) << 1;
    int kx = kb ^ ((ln15 & 7) << 4);
    a_base[kh] = (wr * 64 + ln15) * 128 + kx;
    b_base[kh] = 16384 + (wc * 64 + ln15) * 128 + kx;
  }

  f32x4 acc[4][4];
#pragma unroll
  for (int i = 0; i < 4; i++)
#pragma unroll
    for (int j = 0; j < 4; j++) acc[i][j] = (f32x4)(0.0f);

  float4 pf[8];
  bf16x8 pa[4];
  bf16x8 pb[4];

  auto load_A = [&](int k0) {
    if constexpr (ABF) {
      const unsigned short* s = Ab + arow + k0;
#pragma unroll
      for (int j = 0; j < 4; j++) pa[j] = *(const bf16x8*)(s + 8 * j);
    } else {
      const float* s = Af + arow + k0;
#pragma unroll
      for (int j = 0; j < 8; j++) pf[j] = *(const float4*)(s + 4 * j);
    }
  };
  auto load_B = [&](int k0) {
    const unsigned short* s = Bsrc + k0;
#pragma unroll
    for (int j = 0; j < 4; j++) pb[j] = *(const bf16x8*)(s + 8 * j);
  };

  load_A(kbeg);
  load_B(kbeg);

  for (int k0 = kbeg; k0 < kend; k0 += 64) {
    __syncthreads();
    // ---- store prefetched tile to LDS (swizzled) ----
    if constexpr (ABF) {
#pragma unroll
      for (int j = 0; j < 4; j++) {
        int off = wbaseA + ((sk * 2 + 16 * j) ^ wxor);
        *(bf16x8*)(smem + off) = pa[j];
      }
    } else {
#pragma unroll
      for (int j = 0; j < 8; j++) {
        ushort4 v;
        v.x = f2bf(pf[j].x); v.y = f2bf(pf[j].y);
        v.z = f2bf(pf[j].z); v.w = f2bf(pf[j].w);
        int off = wbaseA + (((sk + 4 * j) * 2) ^ wxor);
        *(ushort4*)(smem + off) = v;
      }
    }
#pragma unroll
    for (int j = 0; j < 4; j++) {
      int off = wbaseB + ((sk * 2 + 16 * j) ^ wxor);
      *(bf16x8*)(smem + off) = pb[j];
    }
    __syncthreads();

    // ---- issue next tile's global loads ----
    int kn = k0 + 64;
    if (kn >= kend) kn = kbeg;  // dummy re-load on last iter (L2-hot)
    load_A(kn);
    load_B(kn);

    // ---- compute: 2 k-halves x 16 MFMA ----
#pragma unroll
    for (int kh = 0; kh < 2; kh++) {
      bf16x8 afr[4], bfr[4];
#pragma unroll
      for (int mi = 0; mi < 4; mi++)
        afr[mi] = *(const bf16x8*)(smem + a_base[kh] + mi * 2048);
#pragma unroll
      for (int ni = 0; ni < 4; ni++)
        bfr[ni] = *(const bf16x8*)(smem + b_base[kh] + ni * 2048);
#pragma unroll
      for (int mi = 0; mi < 4; mi++)
#pragma unroll
        for (int ni = 0; ni < 4; ni++)
          acc[mi][ni] = __builtin_amdgcn_mfma_f32_16x16x32_bf16(
              afr[mi], bfr[ni], acc[mi][ni], 0, 0, 0);
    }
  }

  // ---- epilogue ----
  // C/D layout (16x16x32): col = lane&15, row = (lane>>4)*4 + reg  [m89]
  if constexpr (OMODE == 4) {
    float* P = (float*)Cp + (size_t)ks * N * M;
#pragma unroll
    for (int ni = 0; ni < 4; ni++) {
      int n = bn + wc * 64 + ni * 16 + ln15;
#pragma unroll
      for (int mi = 0; mi < 4; mi++) {
        int m0 = bm + wr * 64 + mi * 16 + (lhi << 2);
        *(f32x4*)(P + (size_t)n * M + m0) = acc[mi][ni];
      }
    }
  } else if constexpr (OMODE == 2) {
    unsigned short* Ct = (unsigned short*)Cp;
#pragma unroll
    for (int ni = 0; ni < 4; ni++) {
      int n = bn + wc * 64 + ni * 16 + ln15;
#pragma unroll
      for (int mi = 0; mi < 4; mi++) {
        int m0 = bm + wr * 64 + mi * 16 + (lhi << 2);
        ushort4 v;
        v.x = f2bf(acc[mi][ni][0]); v.y = f2bf(acc[mi][ni][1]);
        v.z = f2bf(acc[mi][ni][2]); v.w = f2bf(acc[mi][ni][3]);
        *(ushort4*)(Ct + (size_t)n * ldc + m0) = v;
      }
    }
  } else if constexpr (OMODE == 1) {
    unsigned short* Ch = (unsigned short*)Cp;
#pragma unroll
    for (int ni = 0; ni < 4; ni++) {
      int n = bn + wc * 64 + ni * 16 + ln15;
      float bv = BIAS ? bias[n] : 0.0f;
#pragma unroll
      for (int mi = 0; mi < 4; mi++) {
        int m0 = bm + wr * 64 + mi * 16 + (lhi << 2);
#pragma unroll
        for (int r = 0; r < 4; r++) {
          float v = acc[mi][ni][r] + bv;
          if (RELU) v = fmaxf(v, 0.0f);
          Ch[(size_t)(m0 + r) * ldc + n] = f2bf(v);
        }
      }
    }
  } else {
    float* Cf = (float*)Cp;
#pragma unroll
    for (int ni = 0; ni < 4; ni++) {
      int n = bn + wc * 64 + ni * 16 + ln15;
      if (n < nbound) {
        float bv = BIAS ? bias[n] : 0.0f;
#pragma unroll
        for (int mi = 0; mi < 4; mi++) {
          int m0 = bm + wr * 64 + mi * 16 + (lhi << 2);
#pragma unroll
          for (int r = 0; r < 4; r++) {
            float v = acc[mi][ni][r] + bv;
            if (RELU) v = fmaxf(v, 0.0f);
            Cf[(size_t)(m0 + r) * ldc + n] = v;
          }
        }
      }
    }
  }
}

// ---------------------------------------------------------------------------
extern "C" void kernel_launch(void* const* d_in, const int* in_sizes, int n_in,
                              void* d_out, int out_size, void* d_ws, size_t ws_size,
                              hipStream_t stream) {
  (void)in_sizes; (void)n_in; (void)out_size;
  const float* x   = (const float*)d_in[0];
  const float* adj = (const float*)d_in[1];
  const float* W1  = (const float*)d_in[2];
  const float* b1  = (const float*)d_in[3];
  const float* W2  = (const float*)d_in[4];
  const float* b2  = (const float*)d_in[5];

  char* w = (char*)d_ws;
  size_t off = 0;
  auto alloc = [&](size_t bytes) -> char* {
    char* p = w + off;
    off += (bytes + 255) & ~(size_t)255;
    return p;
  };
  unsigned short* W1T   = (unsigned short*)alloc((size_t)FIN * FIN * 2);
  unsigned short* W2T   = (unsigned short*)alloc((size_t)NCLS_PAD * FIN * 2);
  unsigned short* tmp1T = (unsigned short*)alloc((size_t)FIN * NN * 2);
  unsigned short* hbuf  = (unsigned short*)alloc((size_t)NN * FIN * 2);
  unsigned short* tmp2T = (unsigned short*)alloc((size_t)NCLS_PAD * NN * 2);

  const size_t P_BYTES = (size_t)4 * FIN * NN * 4;       // 64 MB (max over A-D)
  const size_t ADJ_BYTES = (size_t)NN * NN * 2;          // 128 MB
  float* Pbuf = nullptr;
  unsigned short* adjb = nullptr;
  if (off + P_BYTES <= ws_size) Pbuf = (float*)alloc(P_BYTES);
  if (off + ADJ_BYTES <= ws_size) adjb = (unsigned short*)alloc(ADJ_BYTES);
  const bool sk = (Pbuf != nullptr);   // split-K enabled
  const bool big = (adjb != nullptr);  // bf16 adj enabled

  dim3 blk(256);

  tconv_kernel<<<dim3(FIN / 32, FIN / 32), dim3(32, 8), 0, stream>>>(W1, W1T, FIN, FIN, FIN);
  tconv_kernel<<<dim3(FIN / 32, NCLS_PAD / 32), dim3(32, 8), 0, stream>>>(W2, W2T, FIN, NCLS, NCLS_PAD);
  if (big)
    conv_adj_kernel<<<dim3((NN * (size_t)NN) / (256 * 4)), blk, 0, stream>>>(adj, adjb);

  // ---- A: tmp1T = (x @ W1)^T   M=8192 N=512 K=512 ----
  if (sk) {
    gemm_kernel<false, 4, false, false, 2><<<dim3(64 * 4 * 2), blk, 0, stream>>>(
        x, W1T, nullptr, Pbuf, NN, FIN, FIN, 0, 0);
    reduce_elem2<<<dim3((FIN * (size_t)NN) / 1024), blk, 0, stream>>>(
        Pbuf, tmp1T, (size_t)FIN * NN);
  } else {
    gemm_kernel<false, 2, false, false, 1><<<dim3(64 * 4), blk, 0, stream>>>(
        x, W1T, nullptr, tmp1T, NN, FIN, FIN, NN, FIN);
  }

  // ---- B: h = relu(adj @ tmp1 + b1)   M=8192 N=512 K=8192 ----
  if (sk) {
    if (big)
      gemm_kernel<true, 4, false, false, 4><<<dim3(64 * 4 * 4), blk, 0, stream>>>(
          adjb, tmp1T, nullptr, Pbuf, NN, FIN, NN, 0, 0);
    else
      gemm_kernel<false, 4, false, false, 4><<<dim3(64 * 4 * 4), blk, 0, stream>>>(
          adj, tmp1T, nullptr, Pbuf, NN, FIN, NN, 0, 0);
    reduce_trans<4, true, false><<<dim3(NN / 64, FIN / 64), blk, 0, stream>>>(
        Pbuf, b1, hbuf, NN, FIN, FIN, FIN);
  } else {
    if (big)
      gemm_kernel<true, 1, true, true, 1><<<dim3(64 * 4), blk, 0, stream>>>(
          adjb, tmp1T, b1, hbuf, NN, FIN, NN, FIN, FIN);
    else
      gemm_kernel<false, 1, true, true, 1><<<dim3(64 * 4), blk, 0, stream>>>(
          adj, tmp1T, b1, hbuf, NN, FIN, NN, FIN, FIN);
  }

  // ---- C: tmp2T = (h @ W2)^T   M=8192 N=384 K=512 ----
  if (sk) {
    gemm_kernel<true, 4, false, false, 2><<<dim3(64 * 3 * 2), blk, 0, stream>>>(
        hbuf, W2T, nullptr, Pbuf, NN, NCLS_PAD, FIN, 0, 0);
    reduce_elem2<<<dim3((NCLS_PAD * (size_t)NN) / 1024), blk, 0, stream>>>(
        Pbuf, tmp2T, (size_t)NCLS_PAD * NN);
  } else {
    gemm_kernel<true, 2, false, false, 1><<<dim3(64 * 3), blk, 0, stream>>>(
        hbuf, W2T, nullptr, tmp2T, NN, NCLS_PAD, FIN, NN, NCLS_PAD);
  }

  // ---- D: out = adj @ tmp2 + b2   M=8192 N=384 K=8192, store n<345 ----
  if (sk) {
    if (big)
      gemm_kernel<true, 4, false, false, 4><<<dim3(64 * 3 * 4), blk, 0, stream>>>(
          adjb, tmp2T, nullptr, Pbuf, NN, NCLS_PAD, NN, 0, 0);
    else
      gemm_kernel<false, 4, false, false, 4><<<dim3(64 * 3 * 4), blk, 0, stream>>>(
          adj, tmp2T, nullptr, Pbuf, NN, NCLS_PAD, NN, 0, 0);
    reduce_trans<4, false, true><<<dim3(NN / 64, NCLS_PAD / 64), blk, 0, stream>>>(
        Pbuf, b2, d_out, NN, NCLS_PAD, NCLS, NCLS);
  } else {
    if (big)
      gemm_kernel<true, 0, true, false, 1><<<dim3(64 * 3), blk, 0, stream>>>(
          adjb, tmp2T, b2, d_out, NN, NCLS_PAD, NN, NCLS, NCLS);
    else
      gemm_kernel<false, 0, true, false, 1><<<dim3(64 * 3), blk, 0, stream>>>(
          adj, tmp2T, b2, d_out, NN, NCLS_PAD, NN, NCLS, NCLS);
  }
}